// Round 1
// 589.463 us; speedup vs baseline: 1.1147x; 1.1147x over previous
//
#include <hip/hip_runtime.h>

// B=64, C=2, N=1024, T=13, D=256
// out: [B,N,N] fp32 = 268 MB; ws: centered ranks as int8 [B,N,D] = 16 MB

typedef __attribute__((ext_vector_type(4))) float f32x4;
typedef __attribute__((ext_vector_type(4))) int   i32x4;

__device__ __forceinline__ void load_lds16(const void* g, void* l) {
  __builtin_amdgcn_global_load_lds(
      (const __attribute__((address_space(1))) void*)g,
      (__attribute__((address_space(3))) void*)l, 16, 0, 0);
}

// ---------------------------------------------------------------------------
// K1: conv (bcnt,dct->bnd) + time-LayerNorm + Spearman rank -> (rank-128) int8
// one block (256 threads) per (b,n) row; thread d owns dim d.
// Rank via bitonic sort (O(D log^2 D)) + branchless binary search, replacing
// the all-pairs O(D^2) count loop (was ~580 VALU/thread, now ~230).
// ---------------------------------------------------------------------------
__global__ __launch_bounds__(256) void conv_rank_kernel(
    const float* __restrict__ x, const float* __restrict__ w,
    const float* __restrict__ cb, const float* __restrict__ tg,
    const float* __restrict__ tb, signed char* __restrict__ ranks)
{
  int row = blockIdx.x;              // b*1024 + n
  int b = row >> 10, n = row & 1023;
  int d = threadIdx.x;
  int wave = d >> 6, lane = d & 63;

  __shared__ float xs[26];
  __shared__ float red[8];
  __shared__ unsigned int ks[256];

  if (d < 26) {
    int c = d / 13, t = d - c * 13;
    xs[d] = x[((size_t)(b * 2 + c) * 1024 + n) * 13 + t];
  }
  __syncthreads();

  // conv: emb_d = cb[d] + sum_{c,t} w[d,c,t] * x[b,c,n,t]  (i = c*13+t)
  const float* wd = w + d * 26;
  float acc = cb[d];
  #pragma unroll
  for (int i = 0; i < 26; ++i) acc += wd[i] * xs[i];

  // time layernorm over D=256 (one value per thread)
  float v1 = acc, v2 = acc * acc;
  #pragma unroll
  for (int o = 32; o > 0; o >>= 1) {
    v1 += __shfl_down(v1, o);
    v2 += __shfl_down(v2, o);
  }
  if (lane == 0) { red[wave * 2] = v1; red[wave * 2 + 1] = v2; }
  __syncthreads();
  float s1 = red[0] + red[2] + red[4] + red[6];
  float s2 = red[1] + red[3] + red[5] + red[7];
  float mu = s1 * (1.0f / 256.0f);
  float var = s2 * (1.0f / 256.0f) - mu * mu;
  float rs = rsqrtf(var + 1e-5f);
  float val = (acc - mu) * rs * tg[d] + tb[d];

  // monotone sortable u32 key
  unsigned int u = __float_as_uint(val);
  unsigned int key = (u & 0x80000000u) ? ~u : (u | 0x80000000u);
  unsigned int okey = key;

  // bitonic sort ascending across the 256 threads (value-only; tie-safe
  // min/max compare-exchange). j<64 -> in-wave shfl_xor; j>=64 -> LDS (3x).
  #pragma unroll
  for (int k = 2; k <= 256; k <<= 1) {
    #pragma unroll
    for (int j = k >> 1; j > 0; j >>= 1) {
      unsigned int pkey;
      if (j < 64) {
        pkey = __shfl_xor(key, j);
      } else {
        ks[d] = key;
        __syncthreads();
        pkey = ks[d ^ j];
        __syncthreads();
      }
      bool keep_min = ((d & j) == 0) == ((d & k) == 0);
      unsigned int mn = key < pkey ? key : pkey;
      unsigned int mx = key < pkey ? pkey : key;
      key = keep_min ? mn : mx;
    }
  }

  // sorted keys -> LDS; rank = lower_bound(okey) = #{j : key_j < okey}
  ks[d] = key;
  __syncthreads();
  int pos = 0;
  #pragma unroll
  for (int s = 128; s > 0; s >>= 1)
    pos += (ks[pos + s - 1] < okey) ? s : 0;

  // store r' = rank - 128 in [-128,127]: exact int8
  ranks[(size_t)row * 256 + d] = (signed char)(pos - 128);
}

// ---------------------------------------------------------------------------
// K2: per batch S = R R^T (1024x1024x256 int8 MFMA, exact i32 accum),
// adj = |S-64| / (norm^2+1e-8).
// m97 structure: 128x128 tile, BK=64, global_load_lds width 16, 4 waves x (64x64)
// i8 halves MFMA cycles (K=64/instr) and halves staged bytes vs bf16.
// ---------------------------------------------------------------------------
__global__ __launch_bounds__(256) void corr_kernel(
    const signed char* __restrict__ ranks, float* __restrict__ out)
{
  int blk = blockIdx.x;
  int b = blk >> 6;
  int tile = blk & 63;
  int trow = (tile >> 3) << 7;
  int tcol = (tile & 7) << 7;
  const signed char* R = ranks + (size_t)b * 1024 * 256;
  float* O = out + (size_t)b * 1024 * 1024;

  __shared__ __align__(16) signed char As[128 * 64];   // 8 KB
  __shared__ __align__(16) signed char Bs[128 * 64];   // 8 KB

  int tid = threadIdx.x;
  int wave = tid >> 6, lane = tid & 63;
  int wrow = (wave >> 1) * 64, wcol = (wave & 1) * 64;

  i32x4 acc[4][4] = {};

  for (int kt = 0; kt < 4; ++kt) {
    int k0 = kt * 64;
    #pragma unroll
    for (int q = 0; q < 2; ++q) {
      int e = q * 4096 + tid * 16;   // byte offset; wave-contiguous LDS dest
      int r = e >> 6;
      int c = e & 63;
      load_lds16(R + (size_t)(trow + r) * 256 + k0 + c, As + e);
      load_lds16(R + (size_t)(tcol + r) * 256 + k0 + c, Bs + e);
    }
    __syncthreads();   // compiler drains vmcnt before s_barrier

    int kq = (lane >> 4) * 16;       // 16 i8 k-elems per lane quad
    i32x4 af[4], bf[4];
    #pragma unroll
    for (int mi = 0; mi < 4; ++mi)
      af[mi] = *(const i32x4*)(As + (wrow + mi * 16 + (lane & 15)) * 64 + kq);
    #pragma unroll
    for (int ni = 0; ni < 4; ++ni)
      bf[ni] = *(const i32x4*)(Bs + (wcol + ni * 16 + (lane & 15)) * 64 + kq);
    #pragma unroll
    for (int mi = 0; mi < 4; ++mi) {
      #pragma unroll
      for (int ni = 0; ni < 4; ++ni)
        acc[mi][ni] = __builtin_amdgcn_mfma_i32_16x16x64_i8(
            af[mi], bf[ni], acc[mi][ni], 0, 0, 0);
    }
    __syncthreads();
  }

  // corr = S - 64 (exact int); denom = norm*norm + 1e-8, norm = sqrt(1398080)
  float nrm = sqrtf(1398080.0f);
  float inv_den = 1.0f / (nrm * nrm + 1e-8f);
  #pragma unroll
  for (int mi = 0; mi < 4; ++mi) {
    int r0 = trow + wrow + mi * 16 + ((lane >> 4) << 2);  // C/D: row=quad*4+reg
    #pragma unroll
    for (int ni = 0; ni < 4; ++ni) {
      int c0 = tcol + wcol + ni * 16 + (lane & 15);       // C/D: col=lane&15
      #pragma unroll
      for (int v = 0; v < 4; ++v) {
        float adj = fabsf((float)(acc[mi][ni][v] - 64)) * inv_den;
        O[(size_t)(r0 + v) * 1024 + c0] = adj;
      }
    }
  }
}

// ---------------------------------------------------------------------------
// K3: in-place LayerNorm over last axis (N=1024) + static_g/static_b + ReLU
// one block per row, thread = one float4
// ---------------------------------------------------------------------------
__global__ __launch_bounds__(256) void ln_relu_kernel(
    float* __restrict__ out, const float* __restrict__ sg,
    const float* __restrict__ sb)
{
  size_t row = blockIdx.x;
  float* p = out + row * 1024;
  int tid = threadIdx.x;
  int wave = tid >> 6, lane = tid & 63;

  float4 v = ((float4*)p)[tid];
  float s1 = v.x + v.y + v.z + v.w;
  float s2 = v.x * v.x + v.y * v.y + v.z * v.z + v.w * v.w;
  #pragma unroll
  for (int o = 32; o > 0; o >>= 1) {
    s1 += __shfl_down(s1, o);
    s2 += __shfl_down(s2, o);
  }
  __shared__ float red[8];
  if (lane == 0) { red[wave * 2] = s1; red[wave * 2 + 1] = s2; }
  __syncthreads();
  float t1 = red[0] + red[2] + red[4] + red[6];
  float t2 = red[1] + red[3] + red[5] + red[7];
  float mu = t1 * (1.0f / 1024.0f);
  float var = t2 * (1.0f / 1024.0f) - mu * mu;
  float rs = rsqrtf(var + 1e-5f);

  float4 g = ((const float4*)sg)[tid];
  float4 bb = ((const float4*)sb)[tid];
  v.x = fmaxf(0.0f, (v.x - mu) * rs * g.x + bb.x);
  v.y = fmaxf(0.0f, (v.y - mu) * rs * g.y + bb.y);
  v.z = fmaxf(0.0f, (v.z - mu) * rs * g.z + bb.z);
  v.w = fmaxf(0.0f, (v.w - mu) * rs * g.w + bb.w);
  ((float4*)p)[tid] = v;
}

extern "C" void kernel_launch(void* const* d_in, const int* in_sizes, int n_in,
                              void* d_out, int out_size, void* d_ws, size_t ws_size,
                              hipStream_t stream) {
  const float* x  = (const float*)d_in[0];
  const float* w  = (const float*)d_in[1];
  const float* cb = (const float*)d_in[2];
  const float* tg = (const float*)d_in[3];
  const float* tb = (const float*)d_in[4];
  const float* sg = (const float*)d_in[5];
  const float* sb = (const float*)d_in[6];
  float* out = (float*)d_out;
  signed char* ranks = (signed char*)d_ws;  // needs 64*1024*256 = 16 MB

  conv_rank_kernel<<<64 * 1024, 256, 0, stream>>>(x, w, cb, tg, tb, ranks);
  corr_kernel<<<64 * 64, 256, 0, stream>>>(ranks, out);
  ln_relu_kernel<<<64 * 1024, 256, 0, stream>>>(out, sg, sb);
}

// Round 2
// 555.107 us; speedup vs baseline: 1.1836x; 1.0619x over previous
//
#include <hip/hip_runtime.h>

// B=64, C=2, N=1024, T=13, D=256
// out: [B,N,N] fp32 = 268 MB; ws: centered ranks as int8 [B,N,D] = 16 MB

typedef __attribute__((ext_vector_type(4))) int i32x4;

__device__ __forceinline__ void load_lds16(const void* g, void* l) {
  __builtin_amdgcn_global_load_lds(
      (const __attribute__((address_space(1))) void*)g,
      (__attribute__((address_space(3))) void*)l, 16, 0, 0);
}

// ---------------------------------------------------------------------------
// K1: conv (bcnt,dct->bnd) + time-LayerNorm + Spearman rank -> (rank-128) int8
// one block (256 threads) per (b,n) row; thread d owns dim d.  (unchanged)
// ---------------------------------------------------------------------------
__global__ __launch_bounds__(256) void conv_rank_kernel(
    const float* __restrict__ x, const float* __restrict__ w,
    const float* __restrict__ cb, const float* __restrict__ tg,
    const float* __restrict__ tb, signed char* __restrict__ ranks)
{
  int row = blockIdx.x;              // b*1024 + n
  int b = row >> 10, n = row & 1023;
  int d = threadIdx.x;
  int wave = d >> 6, lane = d & 63;

  __shared__ float xs[26];
  __shared__ float red[8];
  __shared__ unsigned int ks[256];

  if (d < 26) {
    int c = d / 13, t = d - c * 13;
    xs[d] = x[((size_t)(b * 2 + c) * 1024 + n) * 13 + t];
  }
  __syncthreads();

  const float* wd = w + d * 26;
  float acc = cb[d];
  #pragma unroll
  for (int i = 0; i < 26; ++i) acc += wd[i] * xs[i];

  float v1 = acc, v2 = acc * acc;
  #pragma unroll
  for (int o = 32; o > 0; o >>= 1) {
    v1 += __shfl_down(v1, o);
    v2 += __shfl_down(v2, o);
  }
  if (lane == 0) { red[wave * 2] = v1; red[wave * 2 + 1] = v2; }
  __syncthreads();
  float s1 = red[0] + red[2] + red[4] + red[6];
  float s2 = red[1] + red[3] + red[5] + red[7];
  float mu = s1 * (1.0f / 256.0f);
  float var = s2 * (1.0f / 256.0f) - mu * mu;
  float rs = rsqrtf(var + 1e-5f);
  float val = (acc - mu) * rs * tg[d] + tb[d];

  unsigned int u = __float_as_uint(val);
  unsigned int key = (u & 0x80000000u) ? ~u : (u | 0x80000000u);
  unsigned int okey = key;

  // bitonic sort ascending across 256 threads (value-only, tie-safe)
  #pragma unroll
  for (int k = 2; k <= 256; k <<= 1) {
    #pragma unroll
    for (int j = k >> 1; j > 0; j >>= 1) {
      unsigned int pkey;
      if (j < 64) {
        pkey = __shfl_xor(key, j);
      } else {
        ks[d] = key;
        __syncthreads();
        pkey = ks[d ^ j];
        __syncthreads();
      }
      bool keep_min = ((d & j) == 0) == ((d & k) == 0);
      unsigned int mn = key < pkey ? key : pkey;
      unsigned int mx = key < pkey ? pkey : key;
      key = keep_min ? mn : mx;
    }
  }

  ks[d] = key;
  __syncthreads();
  int pos = 0;
  #pragma unroll
  for (int s = 128; s > 0; s >>= 1)
    pos += (ks[pos + s - 1] < okey) ? s : 0;

  ranks[(size_t)row * 256 + d] = (signed char)(pos - 128);
}

// ---------------------------------------------------------------------------
// K2 (fused): per batch S = R R^T (int8 MFMA, exact i32), adj = |S-64|*inv_den,
// then LayerNorm over the node axis (full 1024-row in-block) + ReLU + store.
// Block = 512 threads (8 waves), computes 32 rows x 1024 cols, K=256.
// LDS tiles k-quad-major [kq][row][16B] -> 2-way (free) bank aliasing on
// ds_read_b128 (row-major was 8-way). global_load_lds stays linear-dest;
// per-lane GLOBAL source does the layout permutation (m173 pattern).
// ---------------------------------------------------------------------------
__global__ __launch_bounds__(512, 4) void corr_ln_kernel(
    const signed char* __restrict__ ranks, const float* __restrict__ sg,
    const float* __restrict__ sb, float* __restrict__ out)
{
  // XCD-chunked swizzle: 2048 blocks, 8 XCDs -> 256 consecutive work items
  // per XCD => each XCD touches 8 batches (8 x 256KB rank panels, L2-fit).
  int bid = blockIdx.x;
  int blk = (bid & 7) * 256 + (bid >> 3);
  int b  = blk >> 5;                  // batch
  int n0 = (blk & 31) << 5;           // row group base (32 rows)
  const signed char* R = ranks + (size_t)b * 1024 * 256;
  float* O = out + ((size_t)b * 1024 + n0) * 1024;

  __shared__ __align__(16) signed char As[8192];    // [kt4][kq4][32][16]
  __shared__ __align__(16) signed char Bs[65536];   // [kq4][1024][16]
  __shared__ float red[8][64];                      // [wave][32 sum | 32 sq]
  __shared__ float stats[2][32];                    // mu, rs per row

  int tid = threadIdx.x;
  int wave = tid >> 6, lane = tid & 63;
  int fr = lane & 15, quad = lane >> 4;
  int cw = wave << 7;                 // 128-col strip per wave

  // stage A (all 32 rows x K=256) once: one 16B/thread issue
  {
    int o = tid * 16;
    int kt_a = o >> 11, kq = (o >> 9) & 3, r32 = (o >> 4) & 31;
    load_lds16(R + (size_t)(n0 + r32) * 256 + kt_a * 64 + kq * 16, As + o);
  }

  i32x4 acc[2][8] = {};

  for (int kt = 0; kt < 4; ++kt) {
    // stage B chunk [kq][1024][16] <- R[row][kt*64 + kq*16 .. +16]
    #pragma unroll
    for (int i = 0; i < 8; ++i) {
      int o = i * 8192 + tid * 16;
      int kq = o >> 14, row = (o & 16383) >> 4;
      load_lds16(R + (size_t)row * 256 + kt * 64 + kq * 16, Bs + o);
    }
    __syncthreads();

    i32x4 af0 = *(const i32x4*)(As + kt * 2048 + quad * 512 + fr * 16);
    i32x4 af1 = *(const i32x4*)(As + kt * 2048 + quad * 512 + (16 + fr) * 16);
    #pragma unroll
    for (int ni = 0; ni < 8; ++ni) {
      i32x4 bf = *(const i32x4*)(Bs + quad * 16384 + (cw + ni * 16 + fr) * 16);
      acc[0][ni] = __builtin_amdgcn_mfma_i32_16x16x64_i8(af0, bf, acc[0][ni], 0, 0, 0);
      acc[1][ni] = __builtin_amdgcn_mfma_i32_16x16x64_i8(af1, bf, acc[1][ni], 0, 0, 0);
    }
    __syncthreads();
  }

  // adj = |S - 64| * inv_den  (exact int S; constants as in verified kernel)
  float nrm = sqrtf(1398080.0f);
  float inv_den = 1.0f / (nrm * nrm + 1e-8f);

  // pass 1: per-row partial sums over this wave's 128-col strip
  float s[2][4], q[2][4];
  #pragma unroll
  for (int mi = 0; mi < 2; ++mi) {
    #pragma unroll
    for (int v = 0; v < 4; ++v) {
      float ss = 0.0f, qq = 0.0f;
      #pragma unroll
      for (int ni = 0; ni < 8; ++ni) {
        float a = fabsf((float)(acc[mi][ni][v] - 64)) * inv_den;
        ss += a; qq += a * a;
      }
      #pragma unroll
      for (int o = 8; o > 0; o >>= 1) {   // reduce across the 16-lane group
        ss += __shfl_xor(ss, o);
        qq += __shfl_xor(qq, o);
      }
      s[mi][v] = ss; q[mi][v] = qq;
    }
  }
  if (fr == 0) {
    #pragma unroll
    for (int mi = 0; mi < 2; ++mi)
      #pragma unroll
      for (int v = 0; v < 4; ++v) {
        int r = mi * 16 + quad * 4 + v;
        red[wave][r] = s[mi][v];
        red[wave][32 + r] = q[mi][v];
      }
  }
  __syncthreads();

  // cross-wave reduce + stats (threads 0..31, one row each)
  if (tid < 32) {
    float su = 0.0f, sq = 0.0f;
    #pragma unroll
    for (int ww = 0; ww < 8; ++ww) { su += red[ww][tid]; sq += red[ww][32 + tid]; }
    float mu = su * (1.0f / 1024.0f);
    float var = sq * (1.0f / 1024.0f) - mu * mu;
    stats[0][tid] = mu;
    stats[1][tid] = rsqrtf(var + 1e-5f);
  }
  __syncthreads();

  // pass 2: normalize + ReLU + store
  float gv[8], bv[8];
  #pragma unroll
  for (int ni = 0; ni < 8; ++ni) {
    int col = cw + ni * 16 + fr;
    gv[ni] = sg[col];
    bv[ni] = sb[col];
  }
  #pragma unroll
  for (int mi = 0; mi < 2; ++mi) {
    #pragma unroll
    for (int v = 0; v < 4; ++v) {
      int r = mi * 16 + quad * 4 + v;
      float mu = stats[0][r], rs = stats[1][r];
      float* orow = O + (size_t)r * 1024;
      #pragma unroll
      for (int ni = 0; ni < 8; ++ni) {
        float a = fabsf((float)(acc[mi][ni][v] - 64)) * inv_den;
        orow[cw + ni * 16 + fr] = fmaxf(0.0f, (a - mu) * rs * gv[ni] + bv[ni]);
      }
    }
  }
}

extern "C" void kernel_launch(void* const* d_in, const int* in_sizes, int n_in,
                              void* d_out, int out_size, void* d_ws, size_t ws_size,
                              hipStream_t stream) {
  const float* x  = (const float*)d_in[0];
  const float* w  = (const float*)d_in[1];
  const float* cb = (const float*)d_in[2];
  const float* tg = (const float*)d_in[3];
  const float* tb = (const float*)d_in[4];
  const float* sg = (const float*)d_in[5];
  const float* sb = (const float*)d_in[6];
  float* out = (float*)d_out;
  signed char* ranks = (signed char*)d_ws;  // 64*1024*256 = 16 MB

  conv_rank_kernel<<<64 * 1024, 256, 0, stream>>>(x, w, cb, tg, tb, ranks);
  corr_ln_kernel<<<2048, 512, 0, stream>>>(ranks, sg, sb, out);
}